// Round 12
// baseline (689.180 us; speedup 1.0000x reference)
//
#include <hip/hip_runtime.h>

#define H 512
#define TSTEPS 196
#define FLEN 784
#define NBATCH 256

typedef float f4 __attribute__((ext_vector_type(4)));
typedef unsigned long long ull;

// ws byte layout:
//   [0MB) Wh1^T  [1MB) Wi2^T   <- L1-list pair (partner = +1MB)
//   [2MB) Wh2^T  [3MB) Wi3^T   <- L2-list pair (partner = +1MB)
//   [4MB) 2KB zero column      <- pad target A
//   [5MB) 2KB zero column      <- pad target B
//   [float 1311232) mask bitmaps mb1,mb2,mb3 (each 196*8 ull)
// List pad VALUES map both pair matrices onto the zero columns:
//   L1 pad = 4MB: bA=0MB -> 4MB zeroA, bB=1MB -> 5MB zeroB
//   L2 pad = 2MB: bA=2MB -> 4MB zeroA, bB=3MB -> 5MB zeroB
#define PAD1 4194304u
#define PAD2 2097152u
#define ZCOL1_F 1048576
#define ZCOL2_F 1310720
#define MBOFF_F 1311232

__global__ void transpose4(const float* __restrict__ a,
                           const float* __restrict__ b,
                           const float* __restrict__ c,
                           const float* __restrict__ d,
                           float* __restrict__ ws)
{
    __shared__ float tile[32][33];
    const float* src = (blockIdx.z == 0) ? a : (blockIdx.z == 1) ? b
                     : (blockIdx.z == 2) ? c : d;
    float* dst = ws + (size_t)blockIdx.z * (H * H);
    int bx = blockIdx.x * 32, by = blockIdx.y * 32;
    int tx = threadIdx.x, ty = threadIdx.y;
    for (int r = ty; r < 32; r += 8)
        tile[r][tx] = src[(by + r) * H + bx + tx];
    __syncthreads();
    for (int r = ty; r < 32; r += 8)
        dst[(bx + r) * H + by + tx] = tile[tx][r];
}

// z<3: pack masks into bitmaps (mb[z][t*8+w] bit l = mask[64w+l, t] != 0)
// z==3: zero the two 2KB pad columns
__global__ void maskbits(const float* __restrict__ m1, const float* __restrict__ m2,
                         const float* __restrict__ m3, float* __restrict__ ws)
{
    int t = blockIdx.x;          // 0..195
    int z = blockIdx.y;          // 0..3
    int l = threadIdx.x;         // 0..63
    if (z == 3) {
        int idx = t * 64 + l;
        if (idx < 512)            ws[ZCOL1_F + idx] = 0.0f;
        else if (idx < 1024)      ws[ZCOL2_F + idx - 512] = 0.0f;
        return;
    }
    ull* mb = (ull*)(ws + MBOFF_F);
    const float* src = (z == 0) ? m1 : (z == 1) ? m2 : m3;
    for (int w = 0; w < 8; ++w) {
        ull bl = __ballot(src[(w * 64 + l) * FLEN + t] != 0.0f);
        if (l == 0) mb[(size_t)z * (TSTEPS * 8) + t * 8 + w] = bl;
    }
}

// Pair gather over list[lo,hi) (lo,hi multiples of 8; entries are byte column
// offsets incl. pad values). One ds_read_b128 per 4 entries; 16 loads in
// flight per iteration; no tail code.
__device__ __forceinline__ void gpair8(const char* __restrict__ bA,
                                       const char* __restrict__ bB,
                                       const int* __restrict__ list,
                                       int lo, int hi, unsigned uoff,
                                       f4& accA, f4& accB)
{
    for (int i = lo; i < hi; i += 8) {
        int4 la = *(const int4*)(list + i);
        int4 lb = *(const int4*)(list + i + 4);
        unsigned o0 = (unsigned)la.x + uoff, o1 = (unsigned)la.y + uoff;
        unsigned o2 = (unsigned)la.z + uoff, o3 = (unsigned)la.w + uoff;
        unsigned o4 = (unsigned)lb.x + uoff, o5 = (unsigned)lb.y + uoff;
        unsigned o6 = (unsigned)lb.z + uoff, o7 = (unsigned)lb.w + uoff;
        f4 va0 = *(const f4*)(bA + o0), vb0 = *(const f4*)(bB + o0);
        f4 va1 = *(const f4*)(bA + o1), vb1 = *(const f4*)(bB + o1);
        f4 va2 = *(const f4*)(bA + o2), vb2 = *(const f4*)(bB + o2);
        f4 va3 = *(const f4*)(bA + o3), vb3 = *(const f4*)(bB + o3);
        f4 va4 = *(const f4*)(bA + o4), vb4 = *(const f4*)(bB + o4);
        f4 va5 = *(const f4*)(bA + o5), vb5 = *(const f4*)(bB + o5);
        f4 va6 = *(const f4*)(bA + o6), vb6 = *(const f4*)(bB + o6);
        f4 va7 = *(const f4*)(bA + o7), vb7 = *(const f4*)(bB + o7);
        accA += ((va0 + va1) + (va2 + va3)) + ((va4 + va5) + (va6 + va7));
        accB += ((vb0 + vb1) + (vb2 + vb3)) + ((vb4 + vb5) + (vb6 + vb7));
    }
}

__device__ __forceinline__ float sum8(const float* __restrict__ p, int j)
{
    float s0 = p[j] + p[512 + j];
    float s1 = p[1024 + j] + p[1536 + j];
    float s2 = p[2048 + j] + p[2560 + j];
    float s3 = p[3072 + j] + p[3584 + j];
    return (s0 + s1) + (s2 + s3);
}

__device__ __forceinline__ float mbit(const ull* __restrict__ mb, int t, int j)
{
    return ((mb[t * 8 + (j >> 6)] >> (j & 63)) & 1ull) ? 1.0f : 0.0f;
}

// lag pipeline, per iteration t = 0..TSTEPS+1:
//   P0: ONE merged gather phase @ lists from t-1 (combined padded index space,
//       [0,na1p) -> L1 pair (Wh1,Wi2), [na1p,tot) -> L2 pair (Wh2,Wi3)):
//       pU1 = Wh1@L1;  pU2 = Wi2@L1 + Wh2@L2;  pU3 = Wi3@L2          | B1
//   P1: lower half U1(t); upper half U2(t-1), U3(t-2); ballots        | B2
//   P2: build ×8-padded lists from ballots                            | B3
__global__ __launch_bounds__(1024)
void lsnn_main(const float* __restrict__ x,
               const float* __restrict__ Wi1,
               const float* __restrict__ bi1, const float* __restrict__ bh1,
               const float* __restrict__ bi2, const float* __restrict__ bh2,
               const float* __restrict__ bi3,
               const float* __restrict__ Wo,  const float* __restrict__ bo,
               const float* __restrict__ tau1, const float* __restrict__ tau2,
               const float* __restrict__ tau3,
               const float* __restrict__ ws,
               float* __restrict__ out)
{
    const char* wsb  = (const char*)ws;
    const char* B_H1 = wsb;
    const char* B_I2 = wsb + (1u << 20);
    const char* B_H2 = wsb + (2u << 20);
    const char* B_I3 = wsb + (3u << 20);
    const ull* mb1 = (const ull*)(ws + MBOFF_F);
    const ull* mb2 = mb1 + TSTEPS * 8;
    const ull* mb3 = mb2 + TSTEPS * 8;

    const int n    = blockIdx.x;
    const int tid  = threadIdx.x;
    const int lane = tid & 63;
    const bool lowh = tid < 512;
    const int j    = lowh ? tid : tid - 512;   // neuron index within half
    const int w8   = (tid >> 6) & 7;           // wave id within half
    const int u    = tid & 127;                // 16B slice id (rows 4u..4u+3)
    const int g    = tid >> 7;                 // gather group 0..7
    const unsigned uoff = (unsigned)u << 4;

    __shared__ f4 pU1[8][128], pU2[8][128], pU3[8][128];
    __shared__ __align__(16) int L1[H], L2[H];
    __shared__ ull ballS[16];    // [0..7]=ball(s1), [8..15]=ball(s2)

    // per-half parameter/state registers
    float4 wi; float bs1, ro1, omr1, mem1, b1, s1;           // lower
    float bs2, ro2, omr2, mem2, b2, s2;                      // upper
    float bs3, ro3, omr3, mem3, b3, s3, cnt3;                // upper
    const float alpha = expf(-1.0f / 20.0f);
    const float oma = 1.0f - alpha;
    if (lowh) {
        wi  = reinterpret_cast<const float4*>(Wi1)[j];
        bs1 = bi1[j] + bh1[j];
        ro1 = expf(-1.0f / tau1[j]); omr1 = 1.0f - ro1;
        mem1 = 0.f; b1 = 0.01f; s1 = 0.f;
    } else {
        bs2 = bi2[j] + bh2[j];
        bs3 = bi3[j];
        ro2 = expf(-1.0f / tau2[j]); omr2 = 1.0f - ro2;
        ro3 = expf(-1.0f / tau3[j]); omr3 = 1.0f - ro3;
        mem2 = 0.f; b2 = 0.01f; s2 = 0.f;
        mem3 = 0.f; b3 = 0.01f; s3 = 0.f; cnt3 = 0.f;
    }

    int na1 = 0, na2 = 0, na1p = 0, na2p = 0;
    const float* xr = x + n * FLEN;

    if (tid < 16) ballS[tid] = 0ull;
    __syncthreads();

    for (int t = 0; t <= TSTEPS + 1; ++t) {
        // ---------------- P0: merged gather (8-unrolled pair walks) --------
        {
            int tot = na1p + na2p;
            int lo = ((tot * g) >> 3) & ~7, hi = ((tot * (g + 1)) >> 3) & ~7;
            if (g == 7) hi = tot;
            f4 aU1 = (f4)0.0f, aU2 = (f4)0.0f, aU3 = (f4)0.0f;
            int mi = lo < na1p ? (hi < na1p ? hi : na1p) : na1p;
            if (lo < mi)
                gpair8(B_H1, B_I2, L1, lo, mi, uoff, aU1, aU2);
            int lo2 = (lo > na1p ? lo : na1p) - na1p, hi2 = hi - na1p;
            if (lo2 < hi2)
                gpair8(B_H2, B_I3, L2, lo2, hi2, uoff, aU2, aU3);
            pU1[g][u] = aU1;
            pU2[g][u] = aU2;
            pU3[g][u] = aU3;
        }
        __syncthreads();                           // B1

        // ---------------- P1: updates (both halves busy) ----------------
        if (lowh) {
            ull ball = 0;
            if (t < TSTEPS) {
                float mk1 = mbit(mb1, t, j);
                int base = (t < 48) ? (4 * t) : (FLEN - 4);
                float4 xv = *reinterpret_cast<const float4*>(xr + base);
                float h1 = wi.x * xv.x + wi.y * xv.y + wi.z * xv.z + wi.w * xv.w
                         + bs1 + sum8((const float*)&pU1[0][0], j);
                b1 = ro1 * b1 + omr1 * s1;
                float Bth = 0.01f + 1.8f * b1;
                float nm = mem1 * alpha + oma * h1 - Bth * s1;
                mem1 = (mk1 == 0.0f) ? mem1 : nm;
                s1 = (mem1 - Bth > 0.0f) ? mk1 : 0.0f;
                ball = __ballot(s1 != 0.0f);
            }
            if (lane == 0) ballS[w8] = ball;
        } else {
            ull ball = 0;
            int t2 = t - 1;
            if (t2 >= 0 && t2 < TSTEPS) {
                float mk2 = mbit(mb2, t2, j);
                float h2 = bs2 + sum8((const float*)&pU2[0][0], j);
                b2 = ro2 * b2 + omr2 * s2;
                float Bth = 0.01f + 1.8f * b2;
                float nm = mem2 * alpha + oma * h2 - Bth * s2;
                mem2 = (mk2 == 0.0f) ? mem2 : nm;
                s2 = (mem2 - Bth > 0.0f) ? mk2 : 0.0f;
                ball = __ballot(s2 != 0.0f);
            }
            if (lane == 0) ballS[8 + w8] = ball;
            int t3 = t - 2;
            if (t3 >= 0 && t3 < TSTEPS) {
                float mk3 = mbit(mb3, t3, j);
                float h3 = bs3 + sum8((const float*)&pU3[0][0], j);
                b3 = ro3 * b3 + omr3 * s3;
                float Bth = 0.01f + 1.8f * b3;
                float nm = mem3 * alpha + oma * h3 - Bth * s3;
                mem3 = (mk3 == 0.0f) ? mem3 : nm;
                s3 = (mem3 - Bth > 0.0f) ? mk3 : 0.0f;
                cnt3 += s3;                        // deferred output GEMV
            }
        }
        __syncthreads();                           // B2

        // ---------------- P2: build ×8-padded lists from ballots ----------
        {
            ull bw[16];
            int c[16];
#pragma unroll
            for (int w = 0; w < 16; ++w) { bw[w] = ballS[w]; c[w] = __popcll(bw[w]); }
            int t1 = 0, t2s = 0;
#pragma unroll
            for (int w = 0; w < 8; ++w) { t1 += c[w]; t2s += c[8 + w]; }
            if (lowh) {
                int pos = 0;
#pragma unroll
                for (int w = 0; w < 8; ++w) if (w < w8) pos += c[w];
                pos += __popcll(bw[w8] & ((1ull << lane) - 1ull));
                if ((bw[w8] >> lane) & 1ull) L1[pos] = j << 11;
            } else {
                int pos = 0;
#pragma unroll
                for (int w = 0; w < 8; ++w) if (w < w8) pos += c[8 + w];
                pos += __popcll(bw[8 + w8] & ((1ull << lane) - 1ull));
                if ((bw[8 + w8] >> lane) & 1ull) L2[pos] = j << 11;
            }
            na1 = t1; na2 = t2s;
            na1p = (na1 + 7) & ~7; na2p = (na2 + 7) & ~7;
            if (tid < 8)       { if (na1 + tid < na1p) L1[na1 + tid] = (int)PAD1; }
            else if (tid < 16) { int q = tid - 8; if (na2 + q < na2p) L2[na2 + q] = (int)PAD2; }
        }
        __syncthreads();                           // B3
    }

    // ---- output: out[n,o] = (Wo[o,:]·cnt3 + T*bo[o]) / T ----
    float* c3 = (float*)&pU1[0][0];
    if (!lowh) c3[j] = cnt3;
    __syncthreads();
    int wv = tid >> 6;   // 0..15
    for (int o = wv; o < 10; o += 16) {
        float p = 0.0f;
        for (int i = lane; i < H; i += 64)
            p += Wo[o * H + i] * c3[i];
        for (int off = 32; off > 0; off >>= 1)
            p += __shfl_down(p, off);
        if (lane == 0)
            out[n * 10 + o] = (p + 196.0f * bo[o]) / 196.0f;
    }
}

extern "C" void kernel_launch(void* const* d_in, const int* in_sizes, int n_in,
                              void* d_out, int out_size, void* d_ws, size_t ws_size,
                              hipStream_t stream)
{
    const float* x    = (const float*)d_in[0];
    const float* Wi1  = (const float*)d_in[1];
    const float* bi1  = (const float*)d_in[2];
    const float* Wh1  = (const float*)d_in[3];
    const float* bh1  = (const float*)d_in[4];
    const float* Wi2  = (const float*)d_in[5];
    const float* bi2  = (const float*)d_in[6];
    const float* Wh2  = (const float*)d_in[7];
    const float* bh2  = (const float*)d_in[8];
    const float* Wi3  = (const float*)d_in[9];
    const float* bi3  = (const float*)d_in[10];
    const float* Wo   = (const float*)d_in[11];
    const float* bo   = (const float*)d_in[12];
    const float* tau1 = (const float*)d_in[13];
    const float* tau2 = (const float*)d_in[14];
    const float* tau3 = (const float*)d_in[15];
    const float* m1   = (const float*)d_in[16];
    const float* m2   = (const float*)d_in[17];
    const float* m3   = (const float*)d_in[18];

    float* ws  = (float*)d_ws;
    float* out = (float*)d_out;

    // pre-pass: transpose Wh1,Wi2,Wh2,Wi3 into 1MB slots; bitmaps + pad cols
    transpose4<<<dim3(16, 16, 4), dim3(32, 8, 1), 0, stream>>>(Wh1, Wi2, Wh2, Wi3, ws);
    maskbits<<<dim3(TSTEPS, 4, 1), 64, 0, stream>>>(m1, m2, m3, ws);

    // main persistent kernel: 1 sample per workgroup (256 WGs, 1024 thr, 16 waves)
    lsnn_main<<<NBATCH, 1024, 0, stream>>>(x, Wi1, bi1, bh1, bi2, bh2, bi3,
                                           Wo, bo, tau1, tau2, tau3, ws, out);
}